// Round 1
// baseline (284.329 us; speedup 1.0000x reference)
//
#include <hip/hip_runtime.h>

// Bilateral slice: grid (4,12,8,16,16) f32, guide (4,1,1024,1024) f32
// out (4,12,1024,1024) f32.
// One thread = 4 consecutive x pixels; float4 guide load, 12x float4 stores.

__global__ __launch_bounds__(256) void bilateral_slice_kernel(
    const float* __restrict__ grid,
    const float* __restrict__ guide,
    float* __restrict__ out)
{
    constexpr int C = 12;
    constexpr float S = 15.0f / 1023.0f;   // linspace(0,15,1024) step

    int t = blockIdx.x * 256 + threadIdx.x;      // 0 .. 1,048,576
    int b = t >> 18;                              // 262144 threads per batch
    int rem = t & 0x3FFFF;
    int y = rem >> 8;                             // row 0..1023
    int xq = rem & 255;                           // quad index
    int xp = xq << 2;                             // first pixel x of this quad

    const float4 gv = *reinterpret_cast<const float4*>(
        guide + ((size_t)b << 20) + (y << 10) + xp);

    // y interpolation (shared by the 4 pixels).
    // min(floor,14) + f = pos - i0 is equivalent to the reference's clip:
    // at pos == 15, f becomes 1.0 and the lerp returns the endpoint.
    float iy = y * S;
    int y0 = min((int)iy, 14);
    float fy = iy - (float)y0;

    const float* gb = grid + (size_t)b * (C * 2048);   // per-batch grid base

    float acc[C][4];
    const float gvals[4] = {gv.x, gv.y, gv.z, gv.w};

    #pragma unroll
    for (int j = 0; j < 4; ++j) {
        float ix = (float)(xp + j) * S;
        int x0 = min((int)ix, 14);
        float fx = ix - (float)x0;

        float gz = fminf(fmaxf(gvals[j], 0.0f), 1.0f) * 7.0f;
        int z0 = min((int)gz, 6);
        float fz = gz - (float)z0;

        int o00 = z0 * 256 + y0 * 16 + x0;   // (z0, y0, x0)
        int o01 = o00 + 16;                  // (z0, y1, x0)
        int o10 = o00 + 256;                 // (z1, y0, x0)
        int o11 = o00 + 272;                 // (z1, y1, x0)

        #pragma unroll
        for (int c = 0; c < C; ++c) {
            const float* p = gb + c * 2048;
            float c000 = p[o00],     c001 = p[o00 + 1];
            float c010 = p[o01],     c011 = p[o01 + 1];
            float c100 = p[o10],     c101 = p[o10 + 1];
            float c110 = p[o11],     c111 = p[o11 + 1];

            float cx0 = fmaf(fx, c001 - c000, c000);
            float cx1 = fmaf(fx, c011 - c010, c010);
            float cy0 = fmaf(fy, cx1 - cx0, cx0);

            float dx0 = fmaf(fx, c101 - c100, c100);
            float dx1 = fmaf(fx, c111 - c110, c110);
            float cy1 = fmaf(fy, dx1 - dx0, dx0);

            acc[c][j] = fmaf(fz, cy1 - cy0, cy0);
        }
    }

    size_t obase = ((size_t)(b * C) << 20) + (size_t)((y << 10) + xp);
    #pragma unroll
    for (int c = 0; c < C; ++c) {
        *reinterpret_cast<float4*>(out + obase + ((size_t)c << 20)) =
            make_float4(acc[c][0], acc[c][1], acc[c][2], acc[c][3]);
    }
}

extern "C" void kernel_launch(void* const* d_in, const int* in_sizes, int n_in,
                              void* d_out, int out_size, void* d_ws, size_t ws_size,
                              hipStream_t stream) {
    const float* grid  = (const float*)d_in[0];
    const float* guide = (const float*)d_in[1];
    float* out = (float*)d_out;

    // 4 batches * 1024 rows * 256 quads = 1,048,576 threads = 4096 blocks
    dim3 grd(4096), blk(256);
    hipLaunchKernelGGL(bilateral_slice_kernel, grd, blk, 0, stream,
                       grid, guide, out);
}

// Round 2
// 47.260 us; speedup vs baseline: 6.0163x; 6.0163x over previous
//
#include <hip/hip_runtime.h>

// Bilateral slice: grid (4,12,8,16,16) f32, guide (4,1,1024,1024) f32
// out (4,12,1024,1024) f32.
// Block = one output row (b,y): y-lerp folded into an 8KB LDS tile
// r[z][x][16] (12 channels as 3 quads, quad position rotated by (q+z)&3 to
// break the z-stride bank alias). Thread = 4 consecutive x pixels.

__global__ __launch_bounds__(256) void bilateral_slice_kernel(
    const float* __restrict__ grid,
    const float* __restrict__ guide,
    float* __restrict__ out)
{
    constexpr int C = 12;
    constexpr float S = 15.0f / 1023.0f;   // linspace step (0..15 over 1024)

    __shared__ float smem[8 * 16 * 16];    // [z][x][16]: 3 rotated channel-quads

    int blk = blockIdx.x;                  // 0..4095
    int b   = blk >> 10;                   // batch
    int y   = blk & 1023;                  // output row

    // Guide load first so its HBM latency overlaps the staging phase.
    int xp = threadIdx.x << 2;             // first pixel of this thread's quad
    const float4 gv = *reinterpret_cast<const float4*>(
        guide + ((size_t)b << 20) + ((size_t)y << 10) + xp);

    // Row-uniform y interpolation. min(floor,14)+f==pos-i0 is equivalent to
    // the reference clip (f->1.0 at the top edge returns the endpoint).
    float iy = y * S;
    int   y0 = min((int)iy, 14);
    float fy = iy - (float)y0;

    // Stage y-interpolated grid row: r[z][x][c] for all 12 c, 8 z, 16 x.
    const float* gb = grid + (size_t)b * (C * 2048) + y0 * 16;
    for (int i = threadIdx.x; i < 1536; i += 256) {
        int c  = i >> 7;                   // 0..11
        int zx = i & 127;                  // z*16 + x
        int z  = zx >> 4;
        int x  = zx & 15;
        const float* p = gb + c * 2048 + z * 256 + x;
        float v0 = p[0], v1 = p[16];       // rows y0, y0+1
        float rv = fmaf(fy, v1 - v0, v0);
        int q   = c >> 2;
        int pos = (((q + z) & 3) << 2) | (c & 3);   // rotated quad slot
        smem[(zx << 4) + pos] = rv;
    }
    __syncthreads();

    float gvals[4] = {gv.x, gv.y, gv.z, gv.w};
    float acc[C][4];

    #pragma unroll
    for (int j = 0; j < 4; ++j) {
        float ix = (float)(xp + j) * S;
        int   x0 = min((int)ix, 14);
        float fx = ix - (float)x0;

        float gz = fminf(fmaxf(gvals[j], 0.0f), 1.0f) * 7.0f;
        int   z0 = min((int)gz, 6);
        float fz = gz - (float)z0;

        int base0 = ((z0 << 4) | x0) << 4;   // (z0, x0) slot
        int base1 = base0 + 256;             // (z0+1, x0): z stride = 16*16

        auto tri = [&](float c00, float c01, float c10, float c11) {
            float e0 = fmaf(fx, c01 - c00, c00);
            float e1 = fmaf(fx, c11 - c10, c10);
            return fmaf(fz, e1 - e0, e0);
        };

        #pragma unroll
        for (int q = 0; q < 3; ++q) {
            int p0 = ((q + z0) & 3) << 2;
            int p1 = ((q + z0 + 1) & 3) << 2;
            const float4 a00 = *reinterpret_cast<const float4*>(&smem[base0 + p0]);
            const float4 a01 = *reinterpret_cast<const float4*>(&smem[base0 + 16 + p0]);
            const float4 a10 = *reinterpret_cast<const float4*>(&smem[base1 + p1]);
            const float4 a11 = *reinterpret_cast<const float4*>(&smem[base1 + 16 + p1]);

            acc[q * 4 + 0][j] = tri(a00.x, a01.x, a10.x, a11.x);
            acc[q * 4 + 1][j] = tri(a00.y, a01.y, a10.y, a11.y);
            acc[q * 4 + 2][j] = tri(a00.z, a01.z, a10.z, a11.z);
            acc[q * 4 + 3][j] = tri(a00.w, a01.w, a10.w, a11.w);
        }
    }

    size_t obase = ((size_t)(b * C) << 20) + (size_t)((y << 10) + xp);
    #pragma unroll
    for (int c = 0; c < C; ++c) {
        *reinterpret_cast<float4*>(out + obase + ((size_t)c << 20)) =
            make_float4(acc[c][0], acc[c][1], acc[c][2], acc[c][3]);
    }
}

extern "C" void kernel_launch(void* const* d_in, const int* in_sizes, int n_in,
                              void* d_out, int out_size, void* d_ws, size_t ws_size,
                              hipStream_t stream) {
    const float* grid  = (const float*)d_in[0];
    const float* guide = (const float*)d_in[1];
    float* out = (float*)d_out;

    // 4 batches * 1024 rows = 4096 blocks; 256 threads = 4 px/thread.
    dim3 grd(4096), blk(256);
    hipLaunchKernelGGL(bilateral_slice_kernel, grd, blk, 0, stream,
                       grid, guide, out);
}